// Round 13
// baseline (6537.548 us; speedup 1.0000x reference)
//
#include <hip/hip_runtime.h>
#include <stdint.h>

// Echo-state network (fp32 in, fp32 out). Round 13: fused-head + pre-split.
// R12 (2276 us, passing, split-f16 MFMA): remaining cost = per-step head kernel
// (re-reads 25 MB state) + in-loop split VALU on the staging critical path.
// Changes (numerics identical: hi + lo*4096 f16 pairs, 3 MFMAs/product):
//  1. W_res/W_in/X pre-split ONCE into persistent f16 hi/lo arrays in d_ws
//     (43.9 MB; ws_size ~268 MB per R12 fill-kernel evidence). State ping-pong
//     stored as f16 hi/lo pairs (split in epilogue). K-loop staging = pure
//     uint4 copies.
//  2. Head fused into the step epilogue: per-lane s * W_lin, 16-lane shuffle
//     reduce, fp32 atomicAdd into logits (pre-initialized with b_lin by init
//     kernel); final argmax kernel writes preds. 1 kernel per timestep.

typedef _Float16 f16;
typedef _Float16 f16x8 __attribute__((ext_vector_type(8)));
typedef float floatx4 __attribute__((ext_vector_type(4)));

#define N_TOT 256
#define T_TOT 70
#define V_TOT 64
#define B_TOT 6
#define H_TOT 1024
#define C_TOT 4
#define F_TOT (B_TOT * H_TOT)
#define LDA 72          // f16 LDS row stride (144 B): <=2-way bank aliasing (free)
#define LO_SCALE 4096.0f
#define LO_INV   (1.0f / 4096.0f)

union H8 { f16 h[8]; uint4 v; };

// ---------------------------------------------------------------------------
// One-time fp32 -> (hi, lo*4096) f16 split, 8 elems/thread. n % 2048 == 0.
// ---------------------------------------------------------------------------
__global__ __launch_bounds__(256)
void split_f32(const float* __restrict__ src, f16* __restrict__ hi,
               f16* __restrict__ lo, int n)
{
    const int i = (blockIdx.x * 256 + threadIdx.x) * 8;
    if (i + 8 > n) return;
    const float4 a = *(const float4*)&src[i];
    const float4 b = *(const float4*)&src[i + 4];
    const float x[8] = {a.x, a.y, a.z, a.w, b.x, b.y, b.z, b.w};
    H8 H, L;
#pragma unroll
    for (int j = 0; j < 8; ++j) {
        const f16 h = (f16)x[j];
        H.h[j] = h;
        L.h[j] = (f16)((x[j] - (float)h) * LO_SCALE);
    }
    *(uint4*)&hi[i] = H.v;
    *(uint4*)&lo[i] = L.v;
}

// ---------------------------------------------------------------------------
// logits[t][n][c] = b_lin[t][c]  (atomic accumulation base)
// ---------------------------------------------------------------------------
__global__ __launch_bounds__(256)
void init_logits(const float* __restrict__ b_lin, float* __restrict__ logits)
{
    const int idx = blockIdx.x * 256 + threadIdx.x;  // < T*N*C = 71680
    if (idx >= T_TOT * N_TOT * C_TOT) return;
    const int c = idx & 3;
    const int t = idx / (N_TOT * C_TOT);
    logits[idx] = b_lin[t * C_TOT + c];
}

// ---------------------------------------------------------------------------
// preds[t][n] = argmax_c logits[t][n][c] (first-index ties)
// ---------------------------------------------------------------------------
__global__ __launch_bounds__(256)
void argmax_preds(const float* __restrict__ logits, float* __restrict__ preds)
{
    const int idx = blockIdx.x * 256 + threadIdx.x;  // < T*N = 17920
    if (idx >= T_TOT * N_TOT) return;
    const float4 l = *(const float4*)&logits[(size_t)idx * 4];
    int arg = 0;
    float best = l.x;
    if (l.y > best) { best = l.y; arg = 1; }
    if (l.z > best) { best = l.z; arg = 2; }
    if (l.w > best) { best = l.w; arg = 3; }
    preds[idx] = (float)arg;
}

// ---------------------------------------------------------------------------
// Fused step+head: S_new = tanh(S W_res^T + X_t W_in^T); logits += S_new.W_lin
// Tile 64(M=batch) x 32(I=units); grid = 6*4*32 = 768. Wave w = M-quadrant,
// 1x2 16x16x32 f16 fragments. BK=64, register-prefetch one chunk ahead.
// All operands pre-split (hi, lo*4096) f16 -> staging is pure uint4 copies.
// ---------------------------------------------------------------------------
__global__ __launch_bounds__(256)
void esn_step_fused(const f16* __restrict__ Xhi,   const f16* __restrict__ Xlo,
                    const f16* __restrict__ Whi,   const f16* __restrict__ Wlo,
                    const f16* __restrict__ Wihi,  const f16* __restrict__ Wilo,
                    const f16* __restrict__ shi_p, const f16* __restrict__ slo_p,
                    f16* __restrict__ shi_n,       f16* __restrict__ slo_n,
                    const float* __restrict__ W_lin, float* __restrict__ logits,
                    int t, int first)
{
    __shared__ f16 As_hi[64 * LDA];
    __shared__ f16 As_lo[64 * LDA];
    __shared__ f16 Bs_hi[32 * LDA];
    __shared__ f16 Bs_lo[32 * LDA];

    const int id  = blockIdx.x;
    const int b   = id >> 7;         // reservoir block 0..5
    const int rem = id & 127;
    const int mt  = rem >> 5;        // batch tile 0..3  (64 rows)
    const int it  = rem & 31;        // unit tile 0..31  (32 cols)

    const int tid  = threadIdx.x;
    const int wm   = tid >> 6;       // wave = M-quadrant
    const int lane = tid & 63;
    const int l16  = lane & 15;
    const int oct  = lane >> 4;

    // staging maps (f16 elements, uint4 = 8 f16)
    const int ra = tid >> 2;          // A row 0..63
    const int ca = (tid & 3) << 4;    // A col {0,16,32,48}: 2 uint4 per buffer
    const int rb = tid >> 3;          // B row 0..31
    const int cb = (tid & 7) << 3;    // B col {0,8,...,56}: 1 uint4 per buffer

    floatx4 acc[2], accl[2];
#pragma unroll
    for (int j = 0; j < 2; ++j) { acc[j] = (floatx4)(0.0f); accl[j] = (floatx4)(0.0f); }

    if (!first) {
        const f16* Ah = shi_p + (size_t)(b * N_TOT + mt * 64 + ra) * H_TOT + ca;
        const f16* Al = slo_p + (size_t)(b * N_TOT + mt * 64 + ra) * H_TOT + ca;
        const f16* Bh = Whi   + (size_t)(b * H_TOT + it * 32 + rb) * H_TOT + cb;
        const f16* Bl = Wlo   + (size_t)(b * H_TOT + it * 32 + rb) * H_TOT + cb;

        uint4 pah0, pah1, pal0, pal1, pbh, pbl;
#define LOAD_CHUNK(J0)                                   \
        do {                                             \
            pah0 = *(const uint4*)&Ah[(J0) + 0];         \
            pah1 = *(const uint4*)&Ah[(J0) + 8];         \
            pal0 = *(const uint4*)&Al[(J0) + 0];         \
            pal1 = *(const uint4*)&Al[(J0) + 8];         \
            pbh  = *(const uint4*)&Bh[(J0)];             \
            pbl  = *(const uint4*)&Bl[(J0)];             \
        } while (0)

        LOAD_CHUNK(0);
        for (int kc = 0; kc < 16; ++kc) {
            if (kc) __syncthreads();   // all waves done reading previous chunk
            *(uint4*)&As_hi[ra * LDA + ca]     = pah0;
            *(uint4*)&As_hi[ra * LDA + ca + 8] = pah1;
            *(uint4*)&As_lo[ra * LDA + ca]     = pal0;
            *(uint4*)&As_lo[ra * LDA + ca + 8] = pal1;
            *(uint4*)&Bs_hi[rb * LDA + cb]     = pbh;
            *(uint4*)&Bs_lo[rb * LDA + cb]     = pbl;
            __syncthreads();
            if (kc < 15) LOAD_CHUNK((kc + 1) * 64);  // overlap w/ ds_read+MFMA

#pragma unroll
            for (int kk = 0; kk < 64; kk += 32) {
                const int ar = (wm * 16 + l16) * LDA + kk + oct * 8;
                const f16x8 ah = *(const f16x8*)&As_hi[ar];
                const f16x8 al = *(const f16x8*)&As_lo[ar];
#pragma unroll
                for (int nf = 0; nf < 2; ++nf) {
                    const int br = (nf * 16 + l16) * LDA + kk + oct * 8;
                    const f16x8 bh = *(const f16x8*)&Bs_hi[br];
                    const f16x8 bl = *(const f16x8*)&Bs_lo[br];
                    acc[nf]  = __builtin_amdgcn_mfma_f32_16x16x32_f16(ah, bh, acc[nf], 0, 0, 0);
                    accl[nf] = __builtin_amdgcn_mfma_f32_16x16x32_f16(ah, bl, accl[nf], 0, 0, 0);
                    accl[nf] = __builtin_amdgcn_mfma_f32_16x16x32_f16(al, bh, accl[nf], 0, 0, 0);
                }
            }
        }
#undef LOAD_CHUNK
        __syncthreads();   // chunk-15 reads done before input-term staging
    }

    // ---- input term: += X_t * W_in[b]^T  (K = V = 64) ----
    {
        const size_t xb = ((size_t)(mt * 64 + ra) * T_TOT + t) * V_TOT + ca;
        *(uint4*)&As_hi[ra * LDA + ca]     = *(const uint4*)&Xhi[xb];
        *(uint4*)&As_hi[ra * LDA + ca + 8] = *(const uint4*)&Xhi[xb + 8];
        *(uint4*)&As_lo[ra * LDA + ca]     = *(const uint4*)&Xlo[xb];
        *(uint4*)&As_lo[ra * LDA + ca + 8] = *(const uint4*)&Xlo[xb + 8];
        const size_t wb = (size_t)(b * H_TOT + it * 32 + rb) * V_TOT + cb;
        *(uint4*)&Bs_hi[rb * LDA + cb] = *(const uint4*)&Wihi[wb];
        *(uint4*)&Bs_lo[rb * LDA + cb] = *(const uint4*)&Wilo[wb];
        __syncthreads();
#pragma unroll
        for (int kk = 0; kk < 64; kk += 32) {
            const int ar = (wm * 16 + l16) * LDA + kk + oct * 8;
            const f16x8 ah = *(const f16x8*)&As_hi[ar];
            const f16x8 al = *(const f16x8*)&As_lo[ar];
#pragma unroll
            for (int nf = 0; nf < 2; ++nf) {
                const int br = (nf * 16 + l16) * LDA + kk + oct * 8;
                const f16x8 bh = *(const f16x8*)&Bs_hi[br];
                const f16x8 bl = *(const f16x8*)&Bs_lo[br];
                acc[nf]  = __builtin_amdgcn_mfma_f32_16x16x32_f16(ah, bh, acc[nf], 0, 0, 0);
                accl[nf] = __builtin_amdgcn_mfma_f32_16x16x32_f16(ah, bl, accl[nf], 0, 0, 0);
                accl[nf] = __builtin_amdgcn_mfma_f32_16x16x32_f16(al, bh, accl[nf], 0, 0, 0);
            }
        }
    }

    // ---- epilogue: tanh -> split-store state; fused head -> atomic logits ----
    // C/D map (16x16x32): col = lane&15, row = oct*4 + r.
    const int nbase = mt * 64;
    const int ibase = it * 32;

    // W_lin slice for this tile: w[c][nf] at feature b*1024 + ibase + nf*16 + l16
    const float* wl = W_lin + (size_t)t * C_TOT * F_TOT + b * H_TOT + ibase;
    float w[4][2];
#pragma unroll
    for (int c = 0; c < 4; ++c)
#pragma unroll
        for (int nf = 0; nf < 2; ++nf)
            w[c][nf] = wl[(size_t)c * F_TOT + nf * 16 + l16];

    float sval[2][4];
#pragma unroll
    for (int nf = 0; nf < 2; ++nf)
#pragma unroll
        for (int r = 0; r < 4; ++r) {
            const int m  = wm * 16 + oct * 4 + r;   // batch row within tile
            const int ii = nf * 16 + l16;           // unit col within tile
            const float s = tanhf(acc[nf][r] + accl[nf][r] * LO_INV);
            sval[nf][r] = s;
            const f16 h = (f16)s;
            const size_t oidx = (size_t)(b * N_TOT + nbase + m) * H_TOT + ibase + ii;
            shi_n[oidx] = h;
            slo_n[oidx] = (f16)((s - (float)h) * LO_SCALE);
        }

#pragma unroll
    for (int r = 0; r < 4; ++r)
#pragma unroll
        for (int c = 0; c < 4; ++c) {
            float v = sval[0][r] * w[c][0] + sval[1][r] * w[c][1];
            v += __shfl_xor(v, 1);
            v += __shfl_xor(v, 2);
            v += __shfl_xor(v, 4);
            v += __shfl_xor(v, 8);
            if (l16 == 0) {
                const int n = nbase + wm * 16 + oct * 4 + r;
                atomicAdd(&logits[((size_t)t * N_TOT + n) * C_TOT + c], v);
            }
        }
}

extern "C" void kernel_launch(void* const* d_in, const int* in_sizes, int n_in,
                              void* d_out, int out_size, void* d_ws, size_t ws_size,
                              hipStream_t stream) {
    const float* X     = (const float*)d_in[0]; // [256,70,64]
    const float* W_res = (const float*)d_in[1]; // [6,1024,1024]
    const float* W_in  = (const float*)d_in[2]; // [6,1024,64]
    const float* W_lin = (const float*)d_in[3]; // [70,4,6144]
    const float* b_lin = (const float*)d_in[4]; // [70,4]

    float* out    = (float*)d_out;
    float* logits = out;                                  // T*N*C fp32
    float* preds  = out + (size_t)T_TOT * N_TOT * C_TOT;  // T*N   fp32

    const size_t nWres = (size_t)B_TOT * H_TOT * H_TOT;   // 6,291,456
    const size_t nWin  = (size_t)B_TOT * H_TOT * V_TOT;   //   393,216
    const size_t nX    = (size_t)N_TOT * T_TOT * V_TOT;   // 1,146,880
    const size_t nS    = (size_t)B_TOT * N_TOT * H_TOT;   // 1,572,864

    f16* p    = (f16*)d_ws;                               // ~43.9 MB total
    f16* Whi  = p;  p += nWres;
    f16* Wlo  = p;  p += nWres;
    f16* Wihi = p;  p += nWin;
    f16* Wilo = p;  p += nWin;
    f16* Xhi  = p;  p += nX;
    f16* Xlo  = p;  p += nX;
    f16* sAh  = p;  p += nS;
    f16* sAl  = p;  p += nS;
    f16* sBh  = p;  p += nS;
    f16* sBl  = p;

    // one-time pre-splits + logits init (stream-ordered before the loop)
    split_f32<<<(int)(nWres / 2048), 256, 0, stream>>>(W_res, Whi, Wlo, (int)nWres);
    split_f32<<<(int)(nWin  / 2048), 256, 0, stream>>>(W_in, Wihi, Wilo, (int)nWin);
    split_f32<<<(int)(nX    / 2048), 256, 0, stream>>>(X, Xhi, Xlo, (int)nX);
    init_logits<<<(T_TOT * N_TOT * C_TOT + 255) / 256, 256, 0, stream>>>(b_lin, logits);

    for (int t = 0; t < T_TOT; ++t) {
        const f16 *ph, *pl;
        f16 *nh, *nl;
        if (t & 1) { ph = sBh; pl = sBl; nh = sAh; nl = sAl; }
        else       { ph = sAh; pl = sAl; nh = sBh; nl = sBl; }
        esn_step_fused<<<B_TOT * 4 * 32, 256, 0, stream>>>(
            Xhi, Xlo, Whi, Wlo, Wihi, Wilo, ph, pl, nh, nl,
            W_lin, logits, t, t == 0 ? 1 : 0);
    }
    argmax_preds<<<(T_TOT * N_TOT + 255) / 256, 256, 0, stream>>>(logits, preds);
}

// Round 14
// 1791.385 us; speedup vs baseline: 3.6494x; 3.6494x over previous
//
#include <hip/hip_runtime.h>
#include <stdint.h>

// Echo-state network (fp32 in, fp32 out). Round 14: fused head WITHOUT atomics.
// R13 post-mortem: 49K device-scope atomicAdds/step onto 256 cachelines of
// d_out serialized cross-XCD (~100 us steps, all pipes idle). Fix: each block
// writes its per-(n,c) partial as ONE non-atomic float4 into part[t][g][n][c]
// (g = b*32+it, 192 groups, 55 MB scratch in the 268-MB ws); a single final
// reduce kernel sums 192 partials + bias -> logits + argmax preds.
// Everything else identical to R13: operands pre-split (hi, lo*4096) f16,
// pure-uint4 LDS staging, register prefetch, 768-block grid, 3 MFMAs/product.

typedef _Float16 f16;
typedef _Float16 f16x8 __attribute__((ext_vector_type(8)));
typedef float floatx4 __attribute__((ext_vector_type(4)));

#define N_TOT 256
#define T_TOT 70
#define V_TOT 64
#define B_TOT 6
#define H_TOT 1024
#define C_TOT 4
#define F_TOT (B_TOT * H_TOT)
#define G_TOT 192       // partial groups = B_TOT * 32 unit-tiles
#define LDA 72          // f16 LDS row stride (144 B): <=2-way bank aliasing (free)
#define LO_SCALE 4096.0f
#define LO_INV   (1.0f / 4096.0f)

union H8 { f16 h[8]; uint4 v; };

// ---------------------------------------------------------------------------
// One-time fp32 -> (hi, lo*4096) f16 split, 8 elems/thread. n % 2048 == 0.
// ---------------------------------------------------------------------------
__global__ __launch_bounds__(256)
void split_f32(const float* __restrict__ src, f16* __restrict__ hi,
               f16* __restrict__ lo, int n)
{
    const int i = (blockIdx.x * 256 + threadIdx.x) * 8;
    if (i + 8 > n) return;
    const float4 a = *(const float4*)&src[i];
    const float4 b = *(const float4*)&src[i + 4];
    const float x[8] = {a.x, a.y, a.z, a.w, b.x, b.y, b.z, b.w};
    H8 H, L;
#pragma unroll
    for (int j = 0; j < 8; ++j) {
        const f16 h = (f16)x[j];
        H.h[j] = h;
        L.h[j] = (f16)((x[j] - (float)h) * LO_SCALE);
    }
    *(uint4*)&hi[i] = H.v;
    *(uint4*)&lo[i] = L.v;
}

// ---------------------------------------------------------------------------
// Final head reduce + argmax. Block = t (70), thread = n (256).
// logits[t][n][c] = b_lin[t][c] + sum_g part[t][g][n][c]; preds = argmax.
// Loads are coalesced: consecutive n -> consecutive float4 for fixed g.
// ---------------------------------------------------------------------------
__global__ __launch_bounds__(256)
void head_reduce(const float* __restrict__ part,
                 const float* __restrict__ b_lin,
                 float* __restrict__ logits,
                 float* __restrict__ preds)
{
    const int t = blockIdx.x;
    const int n = threadIdx.x;

    float a0 = b_lin[t * C_TOT + 0];
    float a1 = b_lin[t * C_TOT + 1];
    float a2 = b_lin[t * C_TOT + 2];
    float a3 = b_lin[t * C_TOT + 3];

    const float* p = part + (((size_t)t * G_TOT) * N_TOT + n) * C_TOT;
    for (int g = 0; g < G_TOT; ++g) {
        const float4 v = *(const float4*)&p[(size_t)g * N_TOT * C_TOT];
        a0 += v.x; a1 += v.y; a2 += v.z; a3 += v.w;
    }

    float4 o = {a0, a1, a2, a3};
    *(float4*)&logits[((size_t)t * N_TOT + n) * C_TOT] = o;

    int arg = 0;
    float best = a0;
    if (a1 > best) { best = a1; arg = 1; }
    if (a2 > best) { best = a2; arg = 2; }
    if (a3 > best) { best = a3; arg = 3; }
    preds[(size_t)t * N_TOT + n] = (float)arg;
}

// ---------------------------------------------------------------------------
// Fused step+head: S_new = tanh(S W_res^T + X_t W_in^T); partials -> part[].
// Tile 64(M=batch) x 32(I=units); grid = 6*4*32 = 768. Wave w = M-quadrant,
// 1x2 16x16x32 f16 fragments. BK=64, register-prefetch one chunk ahead.
// ---------------------------------------------------------------------------
__global__ __launch_bounds__(256)
void esn_step_fused(const f16* __restrict__ Xhi,   const f16* __restrict__ Xlo,
                    const f16* __restrict__ Whi,   const f16* __restrict__ Wlo,
                    const f16* __restrict__ Wihi,  const f16* __restrict__ Wilo,
                    const f16* __restrict__ shi_p, const f16* __restrict__ slo_p,
                    f16* __restrict__ shi_n,       f16* __restrict__ slo_n,
                    const float* __restrict__ W_lin, float* __restrict__ part,
                    int t, int first)
{
    __shared__ f16 As_hi[64 * LDA];
    __shared__ f16 As_lo[64 * LDA];
    __shared__ f16 Bs_hi[32 * LDA];
    __shared__ f16 Bs_lo[32 * LDA];

    const int id  = blockIdx.x;
    const int b   = id >> 7;         // reservoir block 0..5
    const int rem = id & 127;
    const int mt  = rem >> 5;        // batch tile 0..3  (64 rows)
    const int it  = rem & 31;        // unit tile 0..31  (32 cols)

    const int tid  = threadIdx.x;
    const int wm   = tid >> 6;       // wave = M-quadrant
    const int lane = tid & 63;
    const int l16  = lane & 15;
    const int oct  = lane >> 4;

    // staging maps (f16 elements, uint4 = 8 f16)
    const int ra = tid >> 2;          // A row 0..63
    const int ca = (tid & 3) << 4;    // A col {0,16,32,48}: 2 uint4 per buffer
    const int rb = tid >> 3;          // B row 0..31
    const int cb = (tid & 7) << 3;    // B col {0,8,...,56}: 1 uint4 per buffer

    floatx4 acc[2], accl[2];
#pragma unroll
    for (int j = 0; j < 2; ++j) { acc[j] = (floatx4)(0.0f); accl[j] = (floatx4)(0.0f); }

    if (!first) {
        const f16* Ah = shi_p + (size_t)(b * N_TOT + mt * 64 + ra) * H_TOT + ca;
        const f16* Al = slo_p + (size_t)(b * N_TOT + mt * 64 + ra) * H_TOT + ca;
        const f16* Bh = Whi   + (size_t)(b * H_TOT + it * 32 + rb) * H_TOT + cb;
        const f16* Bl = Wlo   + (size_t)(b * H_TOT + it * 32 + rb) * H_TOT + cb;

        uint4 pah0, pah1, pal0, pal1, pbh, pbl;
#define LOAD_CHUNK(J0)                                   \
        do {                                             \
            pah0 = *(const uint4*)&Ah[(J0) + 0];         \
            pah1 = *(const uint4*)&Ah[(J0) + 8];         \
            pal0 = *(const uint4*)&Al[(J0) + 0];         \
            pal1 = *(const uint4*)&Al[(J0) + 8];         \
            pbh  = *(const uint4*)&Bh[(J0)];             \
            pbl  = *(const uint4*)&Bl[(J0)];             \
        } while (0)

        LOAD_CHUNK(0);
        for (int kc = 0; kc < 16; ++kc) {
            if (kc) __syncthreads();   // all waves done reading previous chunk
            *(uint4*)&As_hi[ra * LDA + ca]     = pah0;
            *(uint4*)&As_hi[ra * LDA + ca + 8] = pah1;
            *(uint4*)&As_lo[ra * LDA + ca]     = pal0;
            *(uint4*)&As_lo[ra * LDA + ca + 8] = pal1;
            *(uint4*)&Bs_hi[rb * LDA + cb]     = pbh;
            *(uint4*)&Bs_lo[rb * LDA + cb]     = pbl;
            __syncthreads();
            if (kc < 15) LOAD_CHUNK((kc + 1) * 64);  // overlap w/ ds_read+MFMA

#pragma unroll
            for (int kk = 0; kk < 64; kk += 32) {
                const int ar = (wm * 16 + l16) * LDA + kk + oct * 8;
                const f16x8 ah = *(const f16x8*)&As_hi[ar];
                const f16x8 al = *(const f16x8*)&As_lo[ar];
#pragma unroll
                for (int nf = 0; nf < 2; ++nf) {
                    const int br = (nf * 16 + l16) * LDA + kk + oct * 8;
                    const f16x8 bh = *(const f16x8*)&Bs_hi[br];
                    const f16x8 bl = *(const f16x8*)&Bs_lo[br];
                    acc[nf]  = __builtin_amdgcn_mfma_f32_16x16x32_f16(ah, bh, acc[nf], 0, 0, 0);
                    accl[nf] = __builtin_amdgcn_mfma_f32_16x16x32_f16(ah, bl, accl[nf], 0, 0, 0);
                    accl[nf] = __builtin_amdgcn_mfma_f32_16x16x32_f16(al, bh, accl[nf], 0, 0, 0);
                }
            }
        }
#undef LOAD_CHUNK
        __syncthreads();   // chunk-15 reads done before input-term staging
    }

    // ---- input term: += X_t * W_in[b]^T  (K = V = 64) ----
    {
        const size_t xb = ((size_t)(mt * 64 + ra) * T_TOT + t) * V_TOT + ca;
        *(uint4*)&As_hi[ra * LDA + ca]     = *(const uint4*)&Xhi[xb];
        *(uint4*)&As_hi[ra * LDA + ca + 8] = *(const uint4*)&Xhi[xb + 8];
        *(uint4*)&As_lo[ra * LDA + ca]     = *(const uint4*)&Xlo[xb];
        *(uint4*)&As_lo[ra * LDA + ca + 8] = *(const uint4*)&Xlo[xb + 8];
        const size_t wb = (size_t)(b * H_TOT + it * 32 + rb) * V_TOT + cb;
        *(uint4*)&Bs_hi[rb * LDA + cb] = *(const uint4*)&Wihi[wb];
        *(uint4*)&Bs_lo[rb * LDA + cb] = *(const uint4*)&Wilo[wb];
        __syncthreads();
#pragma unroll
        for (int kk = 0; kk < 64; kk += 32) {
            const int ar = (wm * 16 + l16) * LDA + kk + oct * 8;
            const f16x8 ah = *(const f16x8*)&As_hi[ar];
            const f16x8 al = *(const f16x8*)&As_lo[ar];
#pragma unroll
            for (int nf = 0; nf < 2; ++nf) {
                const int br = (nf * 16 + l16) * LDA + kk + oct * 8;
                const f16x8 bh = *(const f16x8*)&Bs_hi[br];
                const f16x8 bl = *(const f16x8*)&Bs_lo[br];
                acc[nf]  = __builtin_amdgcn_mfma_f32_16x16x32_f16(ah, bh, acc[nf], 0, 0, 0);
                accl[nf] = __builtin_amdgcn_mfma_f32_16x16x32_f16(ah, bl, accl[nf], 0, 0, 0);
                accl[nf] = __builtin_amdgcn_mfma_f32_16x16x32_f16(al, bh, accl[nf], 0, 0, 0);
            }
        }
    }

    // ---- epilogue: tanh -> split-store state; head partial -> part[] ----
    // C/D map (16x16x32): col = lane&15, row = oct*4 + r.
    const int nbase = mt * 64;
    const int ibase = it * 32;

    const float* wl = W_lin + (size_t)t * C_TOT * F_TOT + b * H_TOT + ibase;
    float w[4][2];
#pragma unroll
    for (int c = 0; c < 4; ++c)
#pragma unroll
        for (int nf = 0; nf < 2; ++nf)
            w[c][nf] = wl[(size_t)c * F_TOT + nf * 16 + l16];

    float sval[2][4];
#pragma unroll
    for (int nf = 0; nf < 2; ++nf)
#pragma unroll
        for (int r = 0; r < 4; ++r) {
            const int m  = wm * 16 + oct * 4 + r;   // batch row within tile
            const int ii = nf * 16 + l16;           // unit col within tile
            const float s = tanhf(acc[nf][r] + accl[nf][r] * LO_INV);
            sval[nf][r] = s;
            const f16 h = (f16)s;
            const size_t oidx = (size_t)(b * N_TOT + nbase + m) * H_TOT + ibase + ii;
            shi_n[oidx] = h;
            slo_n[oidx] = (f16)((s - (float)h) * LO_SCALE);
        }

    const int g = b * 32 + it;
#pragma unroll
    for (int r = 0; r < 4; ++r) {
        float v[4];
#pragma unroll
        for (int c = 0; c < 4; ++c) {
            float x = sval[0][r] * w[c][0] + sval[1][r] * w[c][1];
            x += __shfl_xor(x, 1);
            x += __shfl_xor(x, 2);
            x += __shfl_xor(x, 4);
            x += __shfl_xor(x, 8);
            v[c] = x;
        }
        if (l16 == 0) {
            const int n = nbase + wm * 16 + oct * 4 + r;
            float4 o = {v[0], v[1], v[2], v[3]};
            *(float4*)&part[(((size_t)t * G_TOT + g) * N_TOT + n) * C_TOT] = o;
        }
    }
}

extern "C" void kernel_launch(void* const* d_in, const int* in_sizes, int n_in,
                              void* d_out, int out_size, void* d_ws, size_t ws_size,
                              hipStream_t stream) {
    const float* X     = (const float*)d_in[0]; // [256,70,64]
    const float* W_res = (const float*)d_in[1]; // [6,1024,1024]
    const float* W_in  = (const float*)d_in[2]; // [6,1024,64]
    const float* W_lin = (const float*)d_in[3]; // [70,4,6144]
    const float* b_lin = (const float*)d_in[4]; // [70,4]

    float* out    = (float*)d_out;
    float* logits = out;                                  // T*N*C fp32
    float* preds  = out + (size_t)T_TOT * N_TOT * C_TOT;  // T*N   fp32

    const size_t nWres = (size_t)B_TOT * H_TOT * H_TOT;   // 6,291,456
    const size_t nWin  = (size_t)B_TOT * H_TOT * V_TOT;   //   393,216
    const size_t nX    = (size_t)N_TOT * T_TOT * V_TOT;   // 1,146,880
    const size_t nS    = (size_t)B_TOT * N_TOT * H_TOT;   // 1,572,864
    const size_t nPart = (size_t)T_TOT * G_TOT * N_TOT * C_TOT;  // 13,762,560

    f16* p    = (f16*)d_ws;                               // f16 arena ~43.9 MB
    f16* Whi  = p;  p += nWres;
    f16* Wlo  = p;  p += nWres;
    f16* Wihi = p;  p += nWin;
    f16* Wilo = p;  p += nWin;
    f16* Xhi  = p;  p += nX;
    f16* Xlo  = p;  p += nX;
    f16* sAh  = p;  p += nS;
    f16* sAl  = p;  p += nS;
    f16* sBh  = p;  p += nS;
    f16* sBl  = p;  p += nS;
    float* part = (float*)p;                              // +55 MB (ws ~268 MB)

    // one-time pre-splits (stream-ordered before the loop)
    split_f32<<<(int)(nWres / 2048), 256, 0, stream>>>(W_res, Whi, Wlo, (int)nWres);
    split_f32<<<(int)(nWin  / 2048), 256, 0, stream>>>(W_in, Wihi, Wilo, (int)nWin);
    split_f32<<<(int)(nX    / 2048), 256, 0, stream>>>(X, Xhi, Xlo, (int)nX);

    for (int t = 0; t < T_TOT; ++t) {
        const f16 *ph, *pl;
        f16 *nh, *nl;
        if (t & 1) { ph = sBh; pl = sBl; nh = sAh; nl = sAl; }
        else       { ph = sAh; pl = sAl; nh = sBh; nl = sBl; }
        esn_step_fused<<<B_TOT * 4 * 32, 256, 0, stream>>>(
            Xhi, Xlo, Whi, Wlo, Wihi, Wilo, ph, pl, nh, nl,
            W_lin, part, t, t == 0 ? 1 : 0);
    }
    head_reduce<<<T_TOT, 256, 0, stream>>>(part, b_lin, logits, preds);
}